// Round 7
// baseline (335.004 us; speedup 1.0000x reference)
//
#include <hip/hip_runtime.h>
#include <hip/hip_bf16.h>

typedef __attribute__((ext_vector_type(8))) short short8;
typedef __attribute__((ext_vector_type(4))) float f32x4;

__device__ __forceinline__ float bf2f(unsigned short u) {
    unsigned v = ((unsigned)u) << 16;
    float f;
    __builtin_memcpy(&f, &v, 4);
    return f;
}
__device__ __forceinline__ unsigned short f2bf(float f) {
    unsigned v;
    __builtin_memcpy(&v, &f, 4);
    unsigned r = (v + 0x7fffu + ((v >> 16) & 1u)) >> 16;   // RNE
    return (unsigned short)r;
}

#define GLD16(g, l)                                                            \
    __builtin_amdgcn_global_load_lds(                                          \
        (const __attribute__((address_space(1))) void*)(g),                    \
        (__attribute__((address_space(3))) void*)(l), 16, 0, 0)

// ---------------------------------------------------------------- cast x -> bf16
__global__ __launch_bounds__(256) void cast_f32_bf16(const float* __restrict__ in,
                                                     unsigned short* __restrict__ out,
                                                     size_t n) {
    size_t stride = (size_t)gridDim.x * blockDim.x * 4;
    for (size_t i = ((size_t)blockIdx.x * blockDim.x + threadIdx.x) * 4; i < n; i += stride) {
        float4 v = *(const float4*)(in + i);
        ushort4 o;
        o.x = f2bf(v.x); o.y = f2bf(v.y); o.z = f2bf(v.z); o.w = f2bf(v.w);
        *(ushort4*)(out + i) = o;
    }
}

// ------------------------------------------------- cast + transpose W [D][D] -> WT bf16 [n][k]
__global__ __launch_bounds__(256) void cast_transpose_w(const float* __restrict__ W,
                                                        unsigned short* __restrict__ WT, int D) {
    __shared__ float tile[32][33];
    int bx = blockIdx.x * 32;   // col (n) base
    int by = blockIdx.y * 32;   // row (k) base
    int tx = threadIdx.x & 31, ty = threadIdx.x >> 5;   // 32x8
    for (int i = 0; i < 32; i += 8)
        tile[ty + i][tx] = W[(size_t)(by + ty + i) * D + bx + tx];
    __syncthreads();
    for (int i = 0; i < 32; i += 8)
        WT[(size_t)(bx + ty + i) * D + by + tx] = f2bf(tile[tx][ty + i]);
}

// ------------------------------------------------- concat 3 bias vectors
__global__ __launch_bounds__(256) void concat3(const float* __restrict__ a,
                                               const float* __restrict__ b,
                                               const float* __restrict__ c,
                                               float* __restrict__ o, int n) {
    int i = blockIdx.x * 256 + threadIdx.x;
    if (i < n) { o[i] = a[i]; o[n + i] = b[i]; o[2 * n + i] = c[i]; }
}

// ---------------------------------------------------------------- gemm256 v6: 256x256 tile,
// BK=32, 8 waves (2Mx4N), double-buffered LDS = 64 KiB -> 2 blocks/CU (the occupancy A/B:
// r2-r6 all ran 1 block/CU at 128 KiB and plateaued at ~38% MfmaUtil regardless of schedule).
// Per K-step: phase0 {10 ds_read; stage K+1 -> other buf; lgkmcnt(0); 16 MFMA},
// phase1 {2 ds_read; lgkmcnt(0); 16 MFMA}, then vmcnt(0) + ONE barrier. The end-of-step
// drain is covered by the co-resident block (m114 overlap).
// LDS rows 64B; 16B-slot XOR swizzle slot'=slot^((row>>1)&3); global SOURCE pre-swizzled (#21),
// fragment reads apply the same XOR. Conflict-free verified (r3: SQ_LDS_BANK_CONFLICT=0).
// EPI 0: +bias (fp32), store bf16. EPI 1: exp(v*scale), store bf16. EPI 2: store fp32.
template <int EPI>
__global__ __launch_bounds__(512, 2) void gemm256(
    const unsigned short* __restrict__ A, const unsigned short* __restrict__ B,
    void* __restrict__ Cv, const float* __restrict__ bias,
    int K, float scale, int lda, int ldb, int ldc,
    long sA, long sB, long sC) {
    // [buf][op A=0/B=1][256 rows x 32 elems] = 64 KiB
    __shared__ __attribute__((aligned(16))) unsigned short sm[2][2][8192];

    const int tid = threadIdx.x;
    const int wv = tid >> 6, lane = tid & 63;
    const int wm = wv >> 2, wn = wv & 3;
    const int r16 = lane & 15, cHi = lane >> 4;
    const int tileM = blockIdx.y * 256, tileN = blockIdx.x * 256;
    const int bz = blockIdx.z;
    A += (size_t)bz * sA;
    B += (size_t)bz * sB;

    // staging: op-tile = 256 rows x 32 elems (16 KiB); each wave DMAs 2x1KiB per op.
    // staged row = (wv*2+j)*16 + (lane>>2); source 16B-slot pre-swizzled.
    size_t offA[2], offB[2];
    int ldsOff[2];
    const int swzsrc = ((lane & 3) ^ ((lane >> 3) & 3)) * 8;   // element offset of source slot
#pragma unroll
    for (int j = 0; j < 2; ++j) {
        int row = (wv * 2 + j) * 16 + (lane >> 2);
        offA[j] = (size_t)(tileM + row) * lda + swzsrc;
        offB[j] = (size_t)(tileN + row) * ldb + swzsrc;
        ldsOff[j] = (wv * 2 + j) * 1024;               // wave-uniform byte base
    }

    // stage both ops' K-step tile into buffer BUF at k-offset KT
#define STAGE(BUF, KT)                                                          \
    do {                                                                        \
        char* _dA = (char*)&sm[BUF][0][0];                                      \
        char* _dB = (char*)&sm[BUF][1][0];                                      \
        GLD16(A + offA[0] + (KT), _dA + ldsOff[0]);                             \
        GLD16(A + offA[1] + (KT), _dA + ldsOff[1]);                             \
        GLD16(B + offB[0] + (KT), _dB + ldsOff[0]);                             \
        GLD16(B + offB[1] + (KT), _dB + ldsOff[1]);                             \
    } while (0)

    f32x4 acc[8][4];
#pragma unroll
    for (int m = 0; m < 8; ++m)
#pragma unroll
        for (int n = 0; n < 4; ++n) acc[m][n] = (f32x4){0.f, 0.f, 0.f, 0.f};

    // fragment reads: row bits 1-2 come from r16 only -> per-lane xor uniform across m/nf
    const int slotXor = (lane >> 1) & 3;                       // ((row>>1)&3) for row=...+r16
    const int aBase = (wm * 128 + r16) * 32 + (cHi ^ slotXor) * 8;   // +m*512 per m-frag
    const int bBase = (wn * 64 + r16) * 32 + (cHi ^ slotXor) * 8;    // +nf*512 per n-frag

    // prologue: stage K-step 0 into buf 0
    STAGE(0, 0);
    asm volatile("s_waitcnt vmcnt(0)" ::: "memory");
    __builtin_amdgcn_s_barrier();

    short8 aF[8], bF0, bF1;
    const int nt = K >> 5;
    for (int t = 0; t < nt; ++t) {
        const int cur = t & 1, nxt = cur ^ 1;
        const int ktn = (t + 1 == nt) ? 0 : ((t + 1) << 5);   // dummy wraparound stage on last step
        const unsigned short* Abuf = &sm[cur][0][0];
        const unsigned short* Bbuf = &sm[cur][1][0];

        // ---- phase 0: n-half0
#pragma unroll
        for (int m = 0; m < 8; ++m) aF[m] = *(const short8*)&Abuf[aBase + m * 512];
        bF0 = *(const short8*)&Bbuf[bBase];
        bF1 = *(const short8*)&Bbuf[bBase + 512];
        STAGE(nxt, ktn);
        asm volatile("s_waitcnt lgkmcnt(0)" ::: "memory");
        __builtin_amdgcn_sched_barrier(0);
        __builtin_amdgcn_s_setprio(1);
#pragma unroll
        for (int m = 0; m < 8; ++m) {
            acc[m][0] = __builtin_amdgcn_mfma_f32_16x16x32_bf16(aF[m], bF0, acc[m][0], 0, 0, 0);
            acc[m][1] = __builtin_amdgcn_mfma_f32_16x16x32_bf16(aF[m], bF1, acc[m][1], 0, 0, 0);
        }
        __builtin_amdgcn_s_setprio(0);

        // ---- phase 1: n-half1
        bF0 = *(const short8*)&Bbuf[bBase + 1024];
        bF1 = *(const short8*)&Bbuf[bBase + 1536];
        asm volatile("s_waitcnt lgkmcnt(0)" ::: "memory");
        __builtin_amdgcn_sched_barrier(0);
        __builtin_amdgcn_s_setprio(1);
#pragma unroll
        for (int m = 0; m < 8; ++m) {
            acc[m][2] = __builtin_amdgcn_mfma_f32_16x16x32_bf16(aF[m], bF0, acc[m][2], 0, 0, 0);
            acc[m][3] = __builtin_amdgcn_mfma_f32_16x16x32_bf16(aF[m], bF1, acc[m][3], 0, 0, 0);
        }
        __builtin_amdgcn_s_setprio(0);

        // next-step data landed + this buf fully read -> single barrier per K-step
        asm volatile("s_waitcnt vmcnt(0)" ::: "memory");
        __builtin_amdgcn_s_barrier();
    }
#undef STAGE

    // epilogue: C/D layout col=lane&15, row=(lane>>4)*4+reg
    const int rowB = tileM + wm * 128 + cHi * 4;
    const int colB = tileN + wn * 64 + r16;
#pragma unroll
    for (int m = 0; m < 8; ++m) {
#pragma unroll
        for (int n = 0; n < 4; ++n) {
            const int col = colB + n * 16;
            float badd = (EPI == 0) ? bias[col] : 0.f;
#pragma unroll
            for (int r = 0; r < 4; ++r) {
                int row = rowB + m * 16 + r;
                float v = acc[m][n][r];
                if (EPI == 0) v += badd;
                if (EPI == 1) v = __expf(v * scale);
                size_t idx = (size_t)bz * sC + (size_t)row * ldc + col;
                if (EPI == 2) ((float*)Cv)[idx] = v;
                else ((unsigned short*)Cv)[idx] = f2bf(v);
            }
        }
    }
}

// ------------------------------------------ column sums of E (axis=q) -> partials
__global__ __launch_bounds__(256) void col_sum_partial(const unsigned short* __restrict__ E,
                                                       float* __restrict__ partial, int T) {
    int b = blockIdx.z;
    int k = blockIdx.x * 256 + threadIdx.x;
    int q0 = blockIdx.y * 64;
    const unsigned short* p = E + (size_t)b * T * T + (size_t)q0 * T + k;
    float sum = 0.f;
#pragma unroll 4
    for (int q = 0; q < 64; ++q)
        sum += bf2f(p[(size_t)q * T]);
    partial[((size_t)b * gridDim.y + blockIdx.y) * T + k] = sum;
}

__global__ __launch_bounds__(256) void col_sum_reduce(const float* __restrict__ partial,
                                                      float* __restrict__ invl, int T, int nchunk) {
    int b = blockIdx.y;
    int k = blockIdx.x * 256 + threadIdx.x;
    float s = 0.f;
    for (int c = 0; c < nchunk; ++c)
        s += partial[((size_t)b * nchunk + c) * T + k];
    invl[(size_t)b * T + k] = 1.0f / s;
}

// ------------------------------------------ Vt[d][t] = V[t][d] * invl[t]  (per batch)
__global__ __launch_bounds__(256) void transpose_scale_bf16(
    const unsigned short* __restrict__ V, const float* __restrict__ invl,
    unsigned short* __restrict__ Vt, int T, int H, int ldv) {
    __shared__ unsigned short tile[64][66];
    int b = blockIdx.z;
    const unsigned short* Vb = V + (size_t)b * T * ldv;
    unsigned short* Vtb = Vt + (size_t)b * H * T;
    const float* il = invl + (size_t)b * T;
    int x0 = blockIdx.x * 64;   // H dim
    int y0 = blockIdx.y * 64;   // T dim
    int t = threadIdx.x;
    for (int i = 0; i < 16; ++i) {
        int idx = t + i * 256;
        int r = idx >> 6, c = idx & 63;   // r: T-offset, c: H-offset
        tile[r][c] = Vb[(size_t)(y0 + r) * ldv + x0 + c];
    }
    __syncthreads();
    for (int i = 0; i < 16; ++i) {
        int idx = t + i * 256;
        int r = idx >> 6, c = idx & 63;   // r: H-offset, c: T-offset
        float v = bf2f(tile[c][r]) * il[y0 + c];
        Vtb[(size_t)(x0 + r) * T + y0 + c] = f2bf(v);
    }
}

extern "C" void kernel_launch(void* const* d_in, const int* in_sizes, int n_in,
                              void* d_out, int out_size, void* d_ws, size_t ws_size,
                              hipStream_t stream) {
    const int B = 8, T = 2048, H = 1024;
    const size_t MT = (size_t)B * T;   // 16384
    const int H3 = 3 * H;              // 3072

    const float* x  = (const float*)d_in[0];
    const float* Wq = (const float*)d_in[1];
    const float* bq = (const float*)d_in[2];
    const float* Wk = (const float*)d_in[3];
    const float* bk = (const float*)d_in[4];
    const float* Wv = (const float*)d_in[5];
    const float* bv = (const float*)d_in[6];
    float* out = (float*)d_out;

    char* ws = (char*)d_ws;
    size_t o = 0;
    unsigned short* xb   = (unsigned short*)(ws + o); o += MT * H * 2;              // 33.5 MB
    unsigned short* Wcat = (unsigned short*)(ws + o); o += (size_t)H3 * H * 2;      // 6 MB
    float* bcat          = (float*)(ws + o);          o += (size_t)H3 * 4;
    unsigned short* QKVb = (unsigned short*)(ws + o); o += MT * H3 * 2;             // 100.7 MB
    unsigned short* Eb   = (unsigned short*)(ws + o); o += (size_t)B * T * T * 2;   // 67 MB
    float* partial       = (float*)(ws + o);          o += (size_t)B * 32 * T * 4;  // 2 MB
    float* invl          = (float*)(ws + o);          o += (size_t)B * T * 4;
    unsigned short* Vt   = xb;   // xb dead after QKV GEMM; reuse for scaled V^T (33.5 MB)

    // 1. casts + weight concat
    cast_f32_bf16<<<2048, 256, 0, stream>>>(x, xb, MT * H);
    dim3 wgrid(32, 32);
    cast_transpose_w<<<wgrid, 256, 0, stream>>>(Wq, Wcat, H);
    cast_transpose_w<<<wgrid, 256, 0, stream>>>(Wk, Wcat + (size_t)H * H, H);
    cast_transpose_w<<<wgrid, 256, 0, stream>>>(Wv, Wcat + (size_t)2 * H * H, H);
    concat3<<<4, 256, 0, stream>>>(bq, bk, bv, bcat, H);

    // 2. fused QKV projection: [16384,1024] @ [3072,1024]^T + bias -> bf16 interleaved ld=3072
    gemm256<0><<<dim3(H3 / 256, MT / 256, 1), 512, 0, stream>>>(
        xb, Wcat, QKVb, bcat, H, 1.f, H, H, H3, 0, 0, 0);

    // 3. E = exp(Q @ K^T / 32) -> bf16  [B][T][T]
    gemm256<1><<<dim3(T / 256, T / 256, B), 512, 0, stream>>>(
        QKVb, QKVb + H, Eb, nullptr, H, 0.03125f, H3, H3, T,
        (long)T * H3, (long)T * H3, (long)T * T);

    // 4. column (axis=q) sums -> invl
    col_sum_partial<<<dim3(T / 256, 32, B), 256, 0, stream>>>(Eb, partial, T);
    col_sum_reduce<<<dim3(T / 256, B), 256, 0, stream>>>(partial, invl, T, 32);

    // 5. Vt[d][t] = V[t][d] * invl[t]
    transpose_scale_bf16<<<dim3(H / 64, T / 64, B), 256, 0, stream>>>(
        QKVb + 2 * H, invl, Vt, T, H, H3);

    // 6. out = E @ Vt^T -> fp32
    gemm256<2><<<dim3(H / 256, T / 256, B), 512, 0, stream>>>(
        Eb, Vt, out, nullptr, T, 1.f, T, T, H,
        (long)T * T, (long)H * T, (long)T * H);

    (void)in_sizes; (void)n_in; (void)out_size; (void)ws_size;
}

// Round 8
// 305.393 us; speedup vs baseline: 1.0970x; 1.0970x over previous
//
#include <hip/hip_runtime.h>
#include <hip/hip_bf16.h>

typedef __attribute__((ext_vector_type(8))) short short8;
typedef __attribute__((ext_vector_type(4))) float f32x4;

__device__ __forceinline__ float bf2f(unsigned short u) {
    unsigned v = ((unsigned)u) << 16;
    float f;
    __builtin_memcpy(&f, &v, 4);
    return f;
}
__device__ __forceinline__ unsigned short f2bf(float f) {
    unsigned v;
    __builtin_memcpy(&v, &f, 4);
    unsigned r = (v + 0x7fffu + ((v >> 16) & 1u)) >> 16;   // RNE
    return (unsigned short)r;
}

#define GLD16(g, l)                                                            \
    __builtin_amdgcn_global_load_lds(                                          \
        (const __attribute__((address_space(1))) void*)(g),                    \
        (__attribute__((address_space(3))) void*)(l), 16, 0, 0)

// ---------------------------------------------------------------- cast x -> bf16
__global__ __launch_bounds__(256) void cast_f32_bf16(const float* __restrict__ in,
                                                     unsigned short* __restrict__ out,
                                                     size_t n) {
    size_t stride = (size_t)gridDim.x * blockDim.x * 4;
    for (size_t i = ((size_t)blockIdx.x * blockDim.x + threadIdx.x) * 4; i < n; i += stride) {
        float4 v = *(const float4*)(in + i);
        ushort4 o;
        o.x = f2bf(v.x); o.y = f2bf(v.y); o.z = f2bf(v.z); o.w = f2bf(v.w);
        *(ushort4*)(out + i) = o;
    }
}

// ------------------------------------------------- cast + transpose W [D][D] -> WT bf16 [n][k]
__global__ __launch_bounds__(256) void cast_transpose_w(const float* __restrict__ W,
                                                        unsigned short* __restrict__ WT, int D) {
    __shared__ float tile[32][33];
    int bx = blockIdx.x * 32;   // col (n) base
    int by = blockIdx.y * 32;   // row (k) base
    int tx = threadIdx.x & 31, ty = threadIdx.x >> 5;   // 32x8
    for (int i = 0; i < 32; i += 8)
        tile[ty + i][tx] = W[(size_t)(by + ty + i) * D + bx + tx];
    __syncthreads();
    for (int i = 0; i < 32; i += 8)
        WT[(size_t)(bx + ty + i) * D + by + tx] = f2bf(tile[tx][ty + i]);
}

// ------------------------------------------------- concat 3 bias vectors
__global__ __launch_bounds__(256) void concat3(const float* __restrict__ a,
                                               const float* __restrict__ b,
                                               const float* __restrict__ c,
                                               float* __restrict__ o, int n) {
    int i = blockIdx.x * 256 + threadIdx.x;
    if (i < n) { o[i] = a[i]; o[n + i] = b[i]; o[2 * n + i] = c[i]; }
}

// ---------------------------------------------------------------- gemm256 v7: 256x256 tile, BK=64,
// 8 waves (2Mx4N), double-buffered LDS, fine 4-phase/K-tile schedule + T2 swizzle (r6 base).
// NEW: REMAP=1 -> batch<->XCD affinity swizzle (T1): linear block id i, b = i&7 (= XCD via
// round-robin), slot = i>>3, nt-fastest within batch. Each XCD processes exactly one batch ->
// panel reuse becomes XCD-L2-local (r7 evidence: same code = 874 TF on L2-friendly QKV vs
// ~590 TF on scattered QK^T/PV). Pure bijection -> bit-identical output.
// EPI 0: +bias (fp32), store bf16. EPI 1: exp(v*scale), store bf16. EPI 2: store fp32.
template <int EPI, int REMAP>
__global__ __launch_bounds__(512, 2) void gemm256(
    const unsigned short* __restrict__ A, const unsigned short* __restrict__ B,
    void* __restrict__ Cv, const float* __restrict__ bias,
    int K, float scale, int lda, int ldb, int ldc,
    long sA, long sB, long sC) {
    // [buf][kk-half][op A=0/B=1][256 rows x 32 elems] = 128 KiB
    __shared__ __attribute__((aligned(16))) unsigned short sm[2][2][2][8192];

    const int tid = threadIdx.x;
    const int wv = tid >> 6, lane = tid & 63;
    const int wm = wv >> 2, wn = wv & 3;
    const int r16 = lane & 15, cHi = lane >> 4;

    int mt, ntl, bz;
    if (REMAP) {
        // linear id; xcd = i % 8 (round-robin) = batch; slot walks nt fastest
        int i = blockIdx.x + gridDim.x * (blockIdx.y + gridDim.y * blockIdx.z);
        bz = i & 7;
        int slot = i >> 3;
        ntl = slot % gridDim.x;
        mt = slot / gridDim.x;
    } else {
        bz = blockIdx.z; mt = blockIdx.y; ntl = blockIdx.x;
    }
    const int tileM = mt * 256, tileN = ntl * 256;
    A += (size_t)bz * sA;
    B += (size_t)bz * sB;

    // staging: half-tile = 256 rows x 32 elems (16 KiB); each wave DMAs 2x1KiB.
    // staged row = (wv*2+j)*16 + (lane>>2); source 16B-slot pre-swizzled.
    size_t offA[2], offB[2];
    int ldsOff[2];
    const int swzsrc = ((lane & 3) ^ ((lane >> 3) & 3)) * 8;   // element offset of source slot
#pragma unroll
    for (int j = 0; j < 2; ++j) {
        int row = (wv * 2 + j) * 16 + (lane >> 2);
        offA[j] = (size_t)(tileM + row) * lda + swzsrc;
        offB[j] = (size_t)(tileN + row) * ldb + swzsrc;
        ldsOff[j] = (wv * 2 + j) * 1024;               // wave-uniform byte base
    }

#define STAGE(BUF, P, KT)                                                       \
    do {                                                                        \
        const unsigned short* _s = ((P) & 1) ? B : A;                           \
        const size_t* _o = ((P) & 1) ? offB : offA;                             \
        char* _d = (char*)&sm[BUF][(P) >> 1][(P) & 1][0];                       \
        GLD16(_s + _o[0] + (KT) + ((P) >> 1) * 32, _d + ldsOff[0]);             \
        GLD16(_s + _o[1] + (KT) + ((P) >> 1) * 32, _d + ldsOff[1]);             \
    } while (0)

    f32x4 acc[8][4];
#pragma unroll
    for (int m = 0; m < 8; ++m)
#pragma unroll
        for (int n = 0; n < 4; ++n) acc[m][n] = (f32x4){0.f, 0.f, 0.f, 0.f};

    // fragment reads: row bits 1-2 come from r16 only -> per-lane xor uniform across m/nf
    const int slotXor = (lane >> 1) & 3;                       // ((row>>1)&3) for row=...+r16
    const int aBase = (wm * 128 + r16) * 32 + (cHi ^ slotXor) * 8;   // +m*512 per m-frag
    const int bBase = (wn * 64 + r16) * 32 + (cHi ^ slotXor) * 8;    // +nf*512 per n-frag

    // prologue: stage K-tile 0 (4 half-tiles = 8 loads), ensure A_k0,B_k0 landed
    STAGE(0, 0, 0); STAGE(0, 1, 0); STAGE(0, 2, 0); STAGE(0, 3, 0);
    asm volatile("s_waitcnt vmcnt(4)" ::: "memory");
    __builtin_amdgcn_s_barrier();

    short8 aF[8], bF0, bF1;
    const int ktiles = K >> 6;
    for (int t = 0; t < ktiles; ++t) {
        const int cur = t & 1, nxt = cur ^ 1;
        const int ktn = (t + 1 == ktiles) ? 0 : ((t + 1) << 6);   // wraparound dummy stage on last tile
        const unsigned short* A0 = &sm[cur][0][0][0];
        const unsigned short* B0 = &sm[cur][0][1][0];
        const unsigned short* A1 = &sm[cur][1][0][0];
        const unsigned short* B1 = &sm[cur][1][1][0];

        // ---- phase 0: kk0, n-half0
#pragma unroll
        for (int m = 0; m < 8; ++m) aF[m] = *(const short8*)&A0[aBase + m * 512];
        bF0 = *(const short8*)&B0[bBase];
        bF1 = *(const short8*)&B0[bBase + 512];
        STAGE(nxt, 0, ktn);
        __builtin_amdgcn_s_barrier();
        asm volatile("s_waitcnt lgkmcnt(0)" ::: "memory");
        __builtin_amdgcn_sched_barrier(0);
        __builtin_amdgcn_s_setprio(1);
#pragma unroll
        for (int m = 0; m < 8; ++m) {
            acc[m][0] = __builtin_amdgcn_mfma_f32_16x16x32_bf16(aF[m], bF0, acc[m][0], 0, 0, 0);
            acc[m][1] = __builtin_amdgcn_mfma_f32_16x16x32_bf16(aF[m], bF1, acc[m][1], 0, 0, 0);
        }
        __builtin_amdgcn_s_setprio(0);
        __builtin_amdgcn_s_barrier();

        // ---- phase 1: kk0, n-half1
        bF0 = *(const short8*)&B0[bBase + 1024];
        bF1 = *(const short8*)&B0[bBase + 1536];
        STAGE(nxt, 1, ktn);
        __builtin_amdgcn_s_barrier();
        asm volatile("s_waitcnt lgkmcnt(0)" ::: "memory");
        __builtin_amdgcn_sched_barrier(0);
        __builtin_amdgcn_s_setprio(1);
#pragma unroll
        for (int m = 0; m < 8; ++m) {
            acc[m][2] = __builtin_amdgcn_mfma_f32_16x16x32_bf16(aF[m], bF0, acc[m][2], 0, 0, 0);
            acc[m][3] = __builtin_amdgcn_mfma_f32_16x16x32_bf16(aF[m], bF1, acc[m][3], 0, 0, 0);
        }
        __builtin_amdgcn_s_setprio(0);
        asm volatile("s_waitcnt vmcnt(4)" ::: "memory");   // A_k1,B_k1 of this tile landed
        __builtin_amdgcn_s_barrier();

        // ---- phase 2: kk1, n-half0
#pragma unroll
        for (int m = 0; m < 8; ++m) aF[m] = *(const short8*)&A1[aBase + m * 512];
        bF0 = *(const short8*)&B1[bBase];
        bF1 = *(const short8*)&B1[bBase + 512];
        STAGE(nxt, 2, ktn);
        __builtin_amdgcn_s_barrier();
        asm volatile("s_waitcnt lgkmcnt(0)" ::: "memory");
        __builtin_amdgcn_sched_barrier(0);
        __builtin_amdgcn_s_setprio(1);
#pragma unroll
        for (int m = 0; m < 8; ++m) {
            acc[m][0] = __builtin_amdgcn_mfma_f32_16x16x32_bf16(aF[m], bF0, acc[m][0], 0, 0, 0);
            acc[m][1] = __builtin_amdgcn_mfma_f32_16x16x32_bf16(aF[m], bF1, acc[m][1], 0, 0, 0);
        }
        __builtin_amdgcn_s_setprio(0);
        __builtin_amdgcn_s_barrier();

        // ---- phase 3: kk1, n-half1
        bF0 = *(const short8*)&B1[bBase + 1024];
        bF1 = *(const short8*)&B1[bBase + 1536];
        STAGE(nxt, 3, ktn);
        __builtin_amdgcn_s_barrier();
        asm volatile("s_waitcnt lgkmcnt(0)" ::: "memory");
        __builtin_amdgcn_sched_barrier(0);
        __builtin_amdgcn_s_setprio(1);
#pragma unroll
        for (int m = 0; m < 8; ++m) {
            acc[m][2] = __builtin_amdgcn_mfma_f32_16x16x32_bf16(aF[m], bF0, acc[m][2], 0, 0, 0);
            acc[m][3] = __builtin_amdgcn_mfma_f32_16x16x32_bf16(aF[m], bF1, acc[m][3], 0, 0, 0);
        }
        __builtin_amdgcn_s_setprio(0);
        asm volatile("s_waitcnt vmcnt(4)" ::: "memory");   // A_k0,B_k0 of next tile landed
        __builtin_amdgcn_s_barrier();
    }
    asm volatile("s_waitcnt vmcnt(0)" ::: "memory");   // drain wraparound dummy stages
#undef STAGE

    // epilogue: C/D layout col=lane&15, row=(lane>>4)*4+reg
    const int rowB = tileM + wm * 128 + cHi * 4;
    const int colB = tileN + wn * 64 + r16;
#pragma unroll
    for (int m = 0; m < 8; ++m) {
#pragma unroll
        for (int n = 0; n < 4; ++n) {
            const int col = colB + n * 16;
            float badd = (EPI == 0) ? bias[col] : 0.f;
#pragma unroll
            for (int r = 0; r < 4; ++r) {
                int row = rowB + m * 16 + r;
                float v = acc[m][n][r];
                if (EPI == 0) v += badd;
                if (EPI == 1) v = __expf(v * scale);
                size_t idx = (size_t)bz * sC + (size_t)row * ldc + col;
                if (EPI == 2) ((float*)Cv)[idx] = v;
                else ((unsigned short*)Cv)[idx] = f2bf(v);
            }
        }
    }
}

// ------------------------------------------ column sums of E (axis=q) -> partials
__global__ __launch_bounds__(256) void col_sum_partial(const unsigned short* __restrict__ E,
                                                       float* __restrict__ partial, int T) {
    int b = blockIdx.z;
    int k = blockIdx.x * 256 + threadIdx.x;
    int q0 = blockIdx.y * 64;
    const unsigned short* p = E + (size_t)b * T * T + (size_t)q0 * T + k;
    float sum = 0.f;
#pragma unroll 4
    for (int q = 0; q < 64; ++q)
        sum += bf2f(p[(size_t)q * T]);
    partial[((size_t)b * gridDim.y + blockIdx.y) * T + k] = sum;
}

__global__ __launch_bounds__(256) void col_sum_reduce(const float* __restrict__ partial,
                                                      float* __restrict__ invl, int T, int nchunk) {
    int b = blockIdx.y;
    int k = blockIdx.x * 256 + threadIdx.x;
    float s = 0.f;
    for (int c = 0; c < nchunk; ++c)
        s += partial[((size_t)b * nchunk + c) * T + k];
    invl[(size_t)b * T + k] = 1.0f / s;
}

// ------------------------------------------ Vt[d][t] = V[t][d] * invl[t]  (per batch)
__global__ __launch_bounds__(256) void transpose_scale_bf16(
    const unsigned short* __restrict__ V, const float* __restrict__ invl,
    unsigned short* __restrict__ Vt, int T, int H, int ldv) {
    __shared__ unsigned short tile[64][66];
    int b = blockIdx.z;
    const unsigned short* Vb = V + (size_t)b * T * ldv;
    unsigned short* Vtb = Vt + (size_t)b * H * T;
    const float* il = invl + (size_t)b * T;
    int x0 = blockIdx.x * 64;   // H dim
    int y0 = blockIdx.y * 64;   // T dim
    int t = threadIdx.x;
    for (int i = 0; i < 16; ++i) {
        int idx = t + i * 256;
        int r = idx >> 6, c = idx & 63;   // r: T-offset, c: H-offset
        tile[r][c] = Vb[(size_t)(y0 + r) * ldv + x0 + c];
    }
    __syncthreads();
    for (int i = 0; i < 16; ++i) {
        int idx = t + i * 256;
        int r = idx >> 6, c = idx & 63;   // r: H-offset, c: T-offset
        float v = bf2f(tile[c][r]) * il[y0 + c];
        Vtb[(size_t)(x0 + r) * T + y0 + c] = f2bf(v);
    }
}

extern "C" void kernel_launch(void* const* d_in, const int* in_sizes, int n_in,
                              void* d_out, int out_size, void* d_ws, size_t ws_size,
                              hipStream_t stream) {
    const int B = 8, T = 2048, H = 1024;
    const size_t MT = (size_t)B * T;   // 16384
    const int H3 = 3 * H;              // 3072

    const float* x  = (const float*)d_in[0];
    const float* Wq = (const float*)d_in[1];
    const float* bq = (const float*)d_in[2];
    const float* Wk = (const float*)d_in[3];
    const float* bk = (const float*)d_in[4];
    const float* Wv = (const float*)d_in[5];
    const float* bv = (const float*)d_in[6];
    float* out = (float*)d_out;

    char* ws = (char*)d_ws;
    size_t o = 0;
    unsigned short* xb   = (unsigned short*)(ws + o); o += MT * H * 2;              // 33.5 MB
    unsigned short* Wcat = (unsigned short*)(ws + o); o += (size_t)H3 * H * 2;      // 6 MB
    float* bcat          = (float*)(ws + o);          o += (size_t)H3 * 4;
    unsigned short* QKVb = (unsigned short*)(ws + o); o += MT * H3 * 2;             // 100.7 MB
    unsigned short* Eb   = (unsigned short*)(ws + o); o += (size_t)B * T * T * 2;   // 67 MB
    float* partial       = (float*)(ws + o);          o += (size_t)B * 32 * T * 4;  // 2 MB
    float* invl          = (float*)(ws + o);          o += (size_t)B * T * 4;
    unsigned short* Vt   = xb;   // xb dead after QKV GEMM; reuse for scaled V^T (33.5 MB)

    // 1. casts + weight concat
    cast_f32_bf16<<<2048, 256, 0, stream>>>(x, xb, MT * H);
    dim3 wgrid(32, 32);
    cast_transpose_w<<<wgrid, 256, 0, stream>>>(Wq, Wcat, H);
    cast_transpose_w<<<wgrid, 256, 0, stream>>>(Wk, Wcat + (size_t)H * H, H);
    cast_transpose_w<<<wgrid, 256, 0, stream>>>(Wv, Wcat + (size_t)2 * H * H, H);
    concat3<<<4, 256, 0, stream>>>(bq, bk, bv, bcat, H);

    // 2. fused QKV projection: [16384,1024] @ [3072,1024]^T + bias -> bf16 interleaved ld=3072
    gemm256<0, 0><<<dim3(H3 / 256, MT / 256, 1), 512, 0, stream>>>(
        xb, Wcat, QKVb, bcat, H, 1.f, H, H, H3, 0, 0, 0);

    // 3. E = exp(Q @ K^T / 32) -> bf16  [B][T][T]  (batch<->XCD remap)
    gemm256<1, 1><<<dim3(T / 256, T / 256, B), 512, 0, stream>>>(
        QKVb, QKVb + H, Eb, nullptr, H, 0.03125f, H3, H3, T,
        (long)T * H3, (long)T * H3, (long)T * T);

    // 4. column (axis=q) sums -> invl
    col_sum_partial<<<dim3(T / 256, 32, B), 256, 0, stream>>>(Eb, partial, T);
    col_sum_reduce<<<dim3(T / 256, B), 256, 0, stream>>>(partial, invl, T, 32);

    // 5. Vt[d][t] = V[t][d] * invl[t]
    transpose_scale_bf16<<<dim3(H / 64, T / 64, B), 256, 0, stream>>>(
        QKVb + 2 * H, invl, Vt, T, H, H3);

    // 6. out = E @ Vt^T -> fp32  (batch<->XCD remap)
    gemm256<2, 1><<<dim3(H / 256, T / 256, B), 512, 0, stream>>>(
        Eb, Vt, out, nullptr, T, 1.f, T, T, H,
        (long)T * T, (long)H * T, (long)T * H);

    (void)in_sizes; (void)n_in; (void)out_size; (void)ws_size;
}

// Round 9
// 288.505 us; speedup vs baseline: 1.1612x; 1.0585x over previous
//
#include <hip/hip_runtime.h>
#include <hip/hip_bf16.h>

typedef __attribute__((ext_vector_type(8))) short short8;
typedef __attribute__((ext_vector_type(4))) float f32x4;

__device__ __forceinline__ float bf2f(unsigned short u) {
    unsigned v = ((unsigned)u) << 16;
    float f;
    __builtin_memcpy(&f, &v, 4);
    return f;
}
__device__ __forceinline__ unsigned short f2bf(float f) {
    unsigned v;
    __builtin_memcpy(&v, &f, 4);
    unsigned r = (v + 0x7fffu + ((v >> 16) & 1u)) >> 16;   // RNE
    return (unsigned short)r;
}

#define GLD16(g, l)                                                            \
    __builtin_amdgcn_global_load_lds(                                          \
        (const __attribute__((address_space(1))) void*)(g),                    \
        (__attribute__((address_space(3))) void*)(l), 16, 0, 0)

// ---------------------------------------------------------------- cast x -> bf16
__global__ __launch_bounds__(256) void cast_f32_bf16(const float* __restrict__ in,
                                                     unsigned short* __restrict__ out,
                                                     size_t n) {
    size_t stride = (size_t)gridDim.x * blockDim.x * 4;
    for (size_t i = ((size_t)blockIdx.x * blockDim.x + threadIdx.x) * 4; i < n; i += stride) {
        float4 v = *(const float4*)(in + i);
        ushort4 o;
        o.x = f2bf(v.x); o.y = f2bf(v.y); o.z = f2bf(v.z); o.w = f2bf(v.w);
        *(ushort4*)(out + i) = o;
    }
}

// ------------------------------------- cast + transpose 3 weights [D][D] -> WT bf16 [n][k], z-select
__global__ __launch_bounds__(256) void cast_transpose_w3(const float* __restrict__ W0,
                                                         const float* __restrict__ W1,
                                                         const float* __restrict__ W2,
                                                         unsigned short* __restrict__ WT, int D) {
    __shared__ float tile[32][33];
    const float* W = (blockIdx.z == 0) ? W0 : (blockIdx.z == 1) ? W1 : W2;
    unsigned short* dst = WT + (size_t)blockIdx.z * D * D;
    int bx = blockIdx.x * 32;   // col (n) base
    int by = blockIdx.y * 32;   // row (k) base
    int tx = threadIdx.x & 31, ty = threadIdx.x >> 5;   // 32x8
    for (int i = 0; i < 32; i += 8)
        tile[ty + i][tx] = W[(size_t)(by + ty + i) * D + bx + tx];
    __syncthreads();
    for (int i = 0; i < 32; i += 8)
        dst[(size_t)(bx + ty + i) * D + by + tx] = f2bf(tile[tx][ty + i]);
}

// ------------------------------------------------- concat 3 bias vectors
__global__ __launch_bounds__(256) void concat3(const float* __restrict__ a,
                                               const float* __restrict__ b,
                                               const float* __restrict__ c,
                                               float* __restrict__ o, int n) {
    int i = blockIdx.x * 256 + threadIdx.x;
    if (i < n) { o[i] = a[i]; o[n + i] = b[i]; o[2 * n + i] = c[i]; }
}

// ------------------------------------------------- zero a float buffer
__global__ __launch_bounds__(256) void zerof(float* __restrict__ p, int n) {
    int i = blockIdx.x * 256 + threadIdx.x;
    if (i < n) p[i] = 0.f;
}

// ------------------------------------------------- invl = 1/colsum, in place
__global__ __launch_bounds__(256) void recipf(float* __restrict__ p, int n) {
    int i = blockIdx.x * 256 + threadIdx.x;
    if (i < n) p[i] = 1.0f / p[i];
}

// ---------------------------------------------------------------- gemm256 v8: 256x256 tile, BK=64,
// 8 waves (2Mx4N), double-buffered LDS, fine 4-phase/K-tile schedule + T2 swizzle + T1 remap (r8).
// EPI 0: +bias (fp32), store bf16. EPI 1: exp(v*scale), store bf16, AND fused column-sum:
//   per-lane accumulate 4 col partials over m,r -> shfl_xor(16,32) across cHi -> lanes 0-15
//   atomicAdd into csum[bz][col] (csum pre-zeroed each launch). EPI 2: store fp32.
template <int EPI, int REMAP>
__global__ __launch_bounds__(512, 2) void gemm256(
    const unsigned short* __restrict__ A, const unsigned short* __restrict__ B,
    void* __restrict__ Cv, const float* __restrict__ bias, float* __restrict__ csum,
    int K, float scale, int lda, int ldb, int ldc,
    long sA, long sB, long sC) {
    // [buf][kk-half][op A=0/B=1][256 rows x 32 elems] = 128 KiB
    __shared__ __attribute__((aligned(16))) unsigned short sm[2][2][2][8192];

    const int tid = threadIdx.x;
    const int wv = tid >> 6, lane = tid & 63;
    const int wm = wv >> 2, wn = wv & 3;
    const int r16 = lane & 15, cHi = lane >> 4;

    int mt, ntl, bz;
    if (REMAP) {
        // linear id; xcd = i % 8 (round-robin) = batch; slot walks nt fastest
        int i = blockIdx.x + gridDim.x * (blockIdx.y + gridDim.y * blockIdx.z);
        bz = i & 7;
        int slot = i >> 3;
        ntl = slot % gridDim.x;
        mt = slot / gridDim.x;
    } else {
        bz = blockIdx.z; mt = blockIdx.y; ntl = blockIdx.x;
    }
    const int tileM = mt * 256, tileN = ntl * 256;
    A += (size_t)bz * sA;
    B += (size_t)bz * sB;

    // staging: half-tile = 256 rows x 32 elems (16 KiB); each wave DMAs 2x1KiB.
    // staged row = (wv*2+j)*16 + (lane>>2); source 16B-slot pre-swizzled.
    size_t offA[2], offB[2];
    int ldsOff[2];
    const int swzsrc = ((lane & 3) ^ ((lane >> 3) & 3)) * 8;   // element offset of source slot
#pragma unroll
    for (int j = 0; j < 2; ++j) {
        int row = (wv * 2 + j) * 16 + (lane >> 2);
        offA[j] = (size_t)(tileM + row) * lda + swzsrc;
        offB[j] = (size_t)(tileN + row) * ldb + swzsrc;
        ldsOff[j] = (wv * 2 + j) * 1024;               // wave-uniform byte base
    }

#define STAGE(BUF, P, KT)                                                       \
    do {                                                                        \
        const unsigned short* _s = ((P) & 1) ? B : A;                           \
        const size_t* _o = ((P) & 1) ? offB : offA;                             \
        char* _d = (char*)&sm[BUF][(P) >> 1][(P) & 1][0];                       \
        GLD16(_s + _o[0] + (KT) + ((P) >> 1) * 32, _d + ldsOff[0]);             \
        GLD16(_s + _o[1] + (KT) + ((P) >> 1) * 32, _d + ldsOff[1]);             \
    } while (0)

    f32x4 acc[8][4];
#pragma unroll
    for (int m = 0; m < 8; ++m)
#pragma unroll
        for (int n = 0; n < 4; ++n) acc[m][n] = (f32x4){0.f, 0.f, 0.f, 0.f};

    // fragment reads: row bits 1-2 come from r16 only -> per-lane xor uniform across m/nf
    const int slotXor = (lane >> 1) & 3;                       // ((row>>1)&3) for row=...+r16
    const int aBase = (wm * 128 + r16) * 32 + (cHi ^ slotXor) * 8;   // +m*512 per m-frag
    const int bBase = (wn * 64 + r16) * 32 + (cHi ^ slotXor) * 8;    // +nf*512 per n-frag

    // prologue: stage K-tile 0 (4 half-tiles = 8 loads), ensure A_k0,B_k0 landed
    STAGE(0, 0, 0); STAGE(0, 1, 0); STAGE(0, 2, 0); STAGE(0, 3, 0);
    asm volatile("s_waitcnt vmcnt(4)" ::: "memory");
    __builtin_amdgcn_s_barrier();

    short8 aF[8], bF0, bF1;
    const int ktiles = K >> 6;
    for (int t = 0; t < ktiles; ++t) {
        const int cur = t & 1, nxt = cur ^ 1;
        const int ktn = (t + 1 == ktiles) ? 0 : ((t + 1) << 6);   // wraparound dummy stage on last tile
        const unsigned short* A0 = &sm[cur][0][0][0];
        const unsigned short* B0 = &sm[cur][0][1][0];
        const unsigned short* A1 = &sm[cur][1][0][0];
        const unsigned short* B1 = &sm[cur][1][1][0];

        // ---- phase 0: kk0, n-half0
#pragma unroll
        for (int m = 0; m < 8; ++m) aF[m] = *(const short8*)&A0[aBase + m * 512];
        bF0 = *(const short8*)&B0[bBase];
        bF1 = *(const short8*)&B0[bBase + 512];
        STAGE(nxt, 0, ktn);
        __builtin_amdgcn_s_barrier();
        asm volatile("s_waitcnt lgkmcnt(0)" ::: "memory");
        __builtin_amdgcn_sched_barrier(0);
        __builtin_amdgcn_s_setprio(1);
#pragma unroll
        for (int m = 0; m < 8; ++m) {
            acc[m][0] = __builtin_amdgcn_mfma_f32_16x16x32_bf16(aF[m], bF0, acc[m][0], 0, 0, 0);
            acc[m][1] = __builtin_amdgcn_mfma_f32_16x16x32_bf16(aF[m], bF1, acc[m][1], 0, 0, 0);
        }
        __builtin_amdgcn_s_setprio(0);
        __builtin_amdgcn_s_barrier();

        // ---- phase 1: kk0, n-half1
        bF0 = *(const short8*)&B0[bBase + 1024];
        bF1 = *(const short8*)&B0[bBase + 1536];
        STAGE(nxt, 1, ktn);
        __builtin_amdgcn_s_barrier();
        asm volatile("s_waitcnt lgkmcnt(0)" ::: "memory");
        __builtin_amdgcn_sched_barrier(0);
        __builtin_amdgcn_s_setprio(1);
#pragma unroll
        for (int m = 0; m < 8; ++m) {
            acc[m][2] = __builtin_amdgcn_mfma_f32_16x16x32_bf16(aF[m], bF0, acc[m][2], 0, 0, 0);
            acc[m][3] = __builtin_amdgcn_mfma_f32_16x16x32_bf16(aF[m], bF1, acc[m][3], 0, 0, 0);
        }
        __builtin_amdgcn_s_setprio(0);
        asm volatile("s_waitcnt vmcnt(4)" ::: "memory");   // A_k1,B_k1 of this tile landed
        __builtin_amdgcn_s_barrier();

        // ---- phase 2: kk1, n-half0
#pragma unroll
        for (int m = 0; m < 8; ++m) aF[m] = *(const short8*)&A1[aBase + m * 512];
        bF0 = *(const short8*)&B1[bBase];
        bF1 = *(const short8*)&B1[bBase + 512];
        STAGE(nxt, 2, ktn);
        __builtin_amdgcn_s_barrier();
        asm volatile("s_waitcnt lgkmcnt(0)" ::: "memory");
        __builtin_amdgcn_sched_barrier(0);
        __builtin_amdgcn_s_setprio(1);
#pragma unroll
        for (int m = 0; m < 8; ++m) {
            acc[m][0] = __builtin_amdgcn_mfma_f32_16x16x32_bf16(aF[m], bF0, acc[m][0], 0, 0, 0);
            acc[m][1] = __builtin_amdgcn_mfma_f32_16x16x32_bf16(aF[m], bF1, acc[m][1], 0, 0, 0);
        }
        __builtin_amdgcn_s_setprio(0);
        __builtin_amdgcn_s_barrier();

        // ---- phase 3: kk1, n-half1
        bF0 = *(const short8*)&B1[bBase + 1024];
        bF1 = *(const short8*)&B1[bBase + 1536];
        STAGE(nxt, 3, ktn);
        __builtin_amdgcn_s_barrier();
        asm volatile("s_waitcnt lgkmcnt(0)" ::: "memory");
        __builtin_amdgcn_sched_barrier(0);
        __builtin_amdgcn_s_setprio(1);
#pragma unroll
        for (int m = 0; m < 8; ++m) {
            acc[m][2] = __builtin_amdgcn_mfma_f32_16x16x32_bf16(aF[m], bF0, acc[m][2], 0, 0, 0);
            acc[m][3] = __builtin_amdgcn_mfma_f32_16x16x32_bf16(aF[m], bF1, acc[m][3], 0, 0, 0);
        }
        __builtin_amdgcn_s_setprio(0);
        asm volatile("s_waitcnt vmcnt(4)" ::: "memory");   // A_k0,B_k0 of next tile landed
        __builtin_amdgcn_s_barrier();
    }
    asm volatile("s_waitcnt vmcnt(0)" ::: "memory");   // drain wraparound dummy stages
#undef STAGE

    // epilogue: C/D layout col=lane&15, row=(lane>>4)*4+reg
    const int rowB = tileM + wm * 128 + cHi * 4;
    const int colB = tileN + wn * 64 + r16;
    float cs[4] = {0.f, 0.f, 0.f, 0.f};
#pragma unroll
    for (int m = 0; m < 8; ++m) {
#pragma unroll
        for (int n = 0; n < 4; ++n) {
            const int col = colB + n * 16;
            float badd = (EPI == 0) ? bias[col] : 0.f;
#pragma unroll
            for (int r = 0; r < 4; ++r) {
                int row = rowB + m * 16 + r;
                float v = acc[m][n][r];
                if (EPI == 0) v += badd;
                if (EPI == 1) { v = __expf(v * scale); cs[n] += v; }
                size_t idx = (size_t)bz * sC + (size_t)row * ldc + col;
                if (EPI == 2) ((float*)Cv)[idx] = v;
                else ((unsigned short*)Cv)[idx] = f2bf(v);
            }
        }
    }
    if (EPI == 1) {
        // reduce across the 4 cHi groups (rows within this wave's 128-row half)
#pragma unroll
        for (int n = 0; n < 4; ++n) {
            float s = cs[n];
            s += __shfl_xor(s, 16, 64);
            s += __shfl_xor(s, 32, 64);
            if (cHi == 0)
                atomicAdd(&csum[(size_t)bz * ldc + colB + n * 16], s);
        }
    }
}

// ------------------------------------------ Vt[d][t] = V[t][d] * invl[t]  (per batch)
__global__ __launch_bounds__(256) void transpose_scale_bf16(
    const unsigned short* __restrict__ V, const float* __restrict__ invl,
    unsigned short* __restrict__ Vt, int T, int H, int ldv) {
    __shared__ unsigned short tile[64][66];
    int b = blockIdx.z;
    const unsigned short* Vb = V + (size_t)b * T * ldv;
    unsigned short* Vtb = Vt + (size_t)b * H * T;
    const float* il = invl + (size_t)b * T;
    int x0 = blockIdx.x * 64;   // H dim
    int y0 = blockIdx.y * 64;   // T dim
    int t = threadIdx.x;
    for (int i = 0; i < 16; ++i) {
        int idx = t + i * 256;
        int r = idx >> 6, c = idx & 63;   // r: T-offset, c: H-offset
        tile[r][c] = Vb[(size_t)(y0 + r) * ldv + x0 + c];
    }
    __syncthreads();
    for (int i = 0; i < 16; ++i) {
        int idx = t + i * 256;
        int r = idx >> 6, c = idx & 63;   // r: H-offset, c: T-offset
        float v = bf2f(tile[c][r]) * il[y0 + c];
        Vtb[(size_t)(x0 + r) * T + y0 + c] = f2bf(v);
    }
}

extern "C" void kernel_launch(void* const* d_in, const int* in_sizes, int n_in,
                              void* d_out, int out_size, void* d_ws, size_t ws_size,
                              hipStream_t stream) {
    const int B = 8, T = 2048, H = 1024;
    const size_t MT = (size_t)B * T;   // 16384
    const int H3 = 3 * H;              // 3072

    const float* x  = (const float*)d_in[0];
    const float* Wq = (const float*)d_in[1];
    const float* bq = (const float*)d_in[2];
    const float* Wk = (const float*)d_in[3];
    const float* bk = (const float*)d_in[4];
    const float* Wv = (const float*)d_in[5];
    const float* bv = (const float*)d_in[6];
    float* out = (float*)d_out;

    char* ws = (char*)d_ws;
    size_t o = 0;
    unsigned short* xb   = (unsigned short*)(ws + o); o += MT * H * 2;              // 33.5 MB
    unsigned short* Wcat = (unsigned short*)(ws + o); o += (size_t)H3 * H * 2;      // 6 MB
    float* bcat          = (float*)(ws + o);          o += (size_t)H3 * 4;
    unsigned short* QKVb = (unsigned short*)(ws + o); o += MT * H3 * 2;             // 100.7 MB
    unsigned short* Eb   = (unsigned short*)(ws + o); o += (size_t)B * T * T * 2;   // 67 MB
    float* colsum        = (float*)(ws + o);          o += (size_t)B * T * 4;       // 64 KB
    unsigned short* Vt   = xb;   // xb dead after QKV GEMM; reuse for scaled V^T (33.5 MB)

    // 1. casts + weight concat + zero colsum
    cast_f32_bf16<<<2048, 256, 0, stream>>>(x, xb, MT * H);
    cast_transpose_w3<<<dim3(32, 32, 3), 256, 0, stream>>>(Wq, Wk, Wv, Wcat, H);
    concat3<<<4, 256, 0, stream>>>(bq, bk, bv, bcat, H);
    zerof<<<64, 256, 0, stream>>>(colsum, B * T);

    // 2. fused QKV projection: [16384,1024] @ [3072,1024]^T + bias -> bf16 interleaved ld=3072
    gemm256<0, 0><<<dim3(H3 / 256, MT / 256, 1), 512, 0, stream>>>(
        xb, Wcat, QKVb, bcat, nullptr, H, 1.f, H, H, H3, 0, 0, 0);

    // 3. E = exp(Q @ K^T / 32) -> bf16 [B][T][T], fused column sums -> colsum (batch<->XCD remap)
    gemm256<1, 1><<<dim3(T / 256, T / 256, B), 512, 0, stream>>>(
        QKVb, QKVb + H, Eb, nullptr, colsum, H, 0.03125f, H3, H3, T,
        (long)T * H3, (long)T * H3, (long)T * T);

    // 4. invl = 1/colsum (in place)
    recipf<<<64, 256, 0, stream>>>(colsum, B * T);

    // 5. Vt[d][t] = V[t][d] * invl[t]
    transpose_scale_bf16<<<dim3(H / 64, T / 64, B), 256, 0, stream>>>(
        QKVb + 2 * H, colsum, Vt, T, H, H3);

    // 6. out = E @ Vt^T -> fp32  (batch<->XCD remap)
    gemm256<2, 1><<<dim3(H / 256, T / 256, B), 512, 0, stream>>>(
        Eb, Vt, out, nullptr, nullptr, T, 1.f, T, T, H,
        (long)T * T, (long)H * T, (long)T * H);

    (void)in_sizes; (void)n_in; (void)out_size; (void)ws_size;
}